// Round 3
// 1203.345 us; speedup vs baseline: 1.1330x; 1.1330x over previous
//
#include <hip/hip_runtime.h>
#include <hip/hip_bf16.h>
#include <stdint.h>
#include <stddef.h>

// Problem dims: B=1024, T=512, F=8, E=16, H=32, O=1, TO=24

#define LOG2E 1.44269504088896340736f

__device__ __forceinline__ float fast_sigmoid(float x){
    return __builtin_amdgcn_rcpf(1.f + __builtin_amdgcn_exp2f(-LOG2E * x));
}
__device__ __forceinline__ float fast_tanh(float x){
    return 1.f - 2.f * __builtin_amdgcn_rcpf(1.f + __builtin_amdgcn_exp2f(2.f * LOG2E * x));
}
__device__ __forceinline__ float bflo(unsigned u){ return __uint_as_float(u << 16); }
__device__ __forceinline__ float bfhi(unsigned u){ return __uint_as_float(u & 0xffff0000u); }
__device__ __forceinline__ float bperm(int addr, float v){
    return __int_as_float(__builtin_amdgcn_ds_bpermute(addr, __float_as_int(v)));
}

// ---------------------------------------------------------------------------
// Encoder: bidirectional GRU, ONE WAVE per sequence (64 lanes).
// Lane l: j = l&31 (hidden unit), p = l>>5 (K-half). v4: the 24 broadcast
// bpermutes of the verified R0 kernel are replaced by batched ds_read_b128
// from a per-wave LDS row (exact f32 round-trip, value-identical); the
// p-half combine keeps R0's ds_bpermute (4, issued back-to-back = ~1 DS
// latency). No inline asm — the R1/R2 raw v_permlane32_swap_b32 had an
// unmitigated VALU->permlane hazard (sporadic stale reads) and is gone.
// Accumulation chain order is exactly R0's (bias -> 8 e -> 16 h per gate).
// grid 512 x 256 (4 seqs/block, 2048 waves = 2 waves/SIMD).
// ---------------------------------------------------------------------------
__global__ __launch_bounds__(256, 2) void enc_kernel(
    const float* __restrict__ x,
    const float* __restrict__ emb_w, const float* __restrict__ emb_b,
    const float* __restrict__ wih_f, const float* __restrict__ whh_f,
    const float* __restrict__ bih_f, const float* __restrict__ bhh_f,
    const float* __restrict__ wih_b, const float* __restrict__ whh_b,
    const float* __restrict__ bih_b, const float* __restrict__ bhh_b,
    __hip_bfloat16* __restrict__ enc_outT, float* __restrict__ hT)
{
    __shared__ float lme[4][16];
    __shared__ float lh[4][32];

    int tid = threadIdx.x;
    int l = tid & 63;
    int wv = tid >> 6;
    int j = l & 31;
    int p = l >> 5;
    int S = blockIdx.x * 4 + wv;        // 0..2047
    int dir = S >> 10;
    int b = S & 1023;
    const float* wih = dir ? wih_b : wih_f;
    const float* whh = dir ? whh_b : whh_f;
    const float* bih = dir ? bih_b : bih_f;
    const float* bhh = dir ? bhh_b : bhh_f;

    // input-gate weights: e in [8p, 8p+8)
    float wr[8], wz[8], wn[8];
#pragma unroll
    for (int e = 0; e < 8; e++){
        int ee = 8 * p + e;
        wr[e] = wih[j * 16 + ee];
        wz[e] = wih[(32 + j) * 16 + ee];
        wn[e] = wih[(64 + j) * 16 + ee];
    }
    // hidden-gate weights: k in [16p, 16p+16)
    float ur[16], uz[16], un[16];
#pragma unroll
    for (int k = 0; k < 16; k++){
        int kk = 16 * p + k;
        ur[k] = whh[j * 32 + kk];
        uz[k] = whh[(32 + j) * 32 + kk];
        un[k] = whh[(64 + j) * 32 + kk];
    }
    // biases folded into p==0 lane's accumulator init (counted once after combine)
    float c_r  = p ? 0.f : (bih[j] + bhh[j]);
    float c_z  = p ? 0.f : (bih[32 + j] + bhh[32 + j]);
    float c_ni = p ? 0.f : bih[64 + j];
    float c_nh = p ? 0.f : bhh[64 + j];

    float ew[8];
#pragma unroll
    for (int f = 0; f < 8; f++) ew[f] = emb_w[(l & 15) * 8 + f];
    float ebias = emb_b[l & 15];

    int aX = 4 * (l ^ 32);   // bpermute byte address for the half-combine

    float h = 0.f;
    const float* xp = x + (size_t)b * 4096 + (dir ? 511 * 8 : 0);
    __hip_bfloat16* op = enc_outT + ((size_t)b * 512 + (dir ? 511 : 0)) * 64 + dir * 32 + j;
    int xstep = dir ? -8 : 8;
    ptrdiff_t ostep = dir ? -64 : 64;

    float4 cx0 = ((const float4*)xp)[0];
    float4 cx1 = ((const float4*)xp)[1];

    // me for t=0
    float me;
    {
        float e0 = ebias;
        e0 = fmaf(cx0.x, ew[0], e0); e0 = fmaf(cx0.y, ew[1], e0);
        e0 = fmaf(cx0.z, ew[2], e0); e0 = fmaf(cx0.w, ew[3], e0);
        e0 = fmaf(cx1.x, ew[4], e0); e0 = fmaf(cx1.y, ew[5], e0);
        e0 = fmaf(cx1.z, ew[6], e0); e0 = fmaf(cx1.w, ew[7], e0);
        me = fmaxf(e0, 0.f);
    }
    if (l < 16) lme[wv][l] = me;   // lanes 0..15 hold me[0..15]
    if (l < 32) lh[wv][l] = h;     // p0 half holds h[0..31]

    const float4* pe = (const float4*)(&lme[wv][8 * p]);
    const float4* ph = (const float4*)(&lh[wv][16 * p]);

    for (int it = 0; it < 512; ++it){
        // prefetch next x (clamped on last iter)
        const float* np = (it == 511) ? xp : (xp + xstep);
        float4 nx0 = ((const float4*)np)[0];
        float4 nx1 = ((const float4*)np)[1];

        // batched LDS broadcast reads (one DS latency for all six)
        float4 e01 = pe[0], e23 = pe[1];
        float4 h0 = ph[0], h1 = ph[1], h2 = ph[2], h3 = ph[3];

        // gate accumulators — SAME chain order as the verified R0 kernel:
        // bias, then e[0..7], then h[0..15], single chain each.
        float Ar = c_r, Az = c_z, Ani = c_ni, Anh = c_nh;

        Ar = fmaf(e01.x, wr[0], Ar); Az = fmaf(e01.x, wz[0], Az); Ani = fmaf(e01.x, wn[0], Ani);
        Ar = fmaf(e01.y, wr[1], Ar); Az = fmaf(e01.y, wz[1], Az); Ani = fmaf(e01.y, wn[1], Ani);
        Ar = fmaf(e01.z, wr[2], Ar); Az = fmaf(e01.z, wz[2], Az); Ani = fmaf(e01.z, wn[2], Ani);
        Ar = fmaf(e01.w, wr[3], Ar); Az = fmaf(e01.w, wz[3], Az); Ani = fmaf(e01.w, wn[3], Ani);
        Ar = fmaf(e23.x, wr[4], Ar); Az = fmaf(e23.x, wz[4], Az); Ani = fmaf(e23.x, wn[4], Ani);
        Ar = fmaf(e23.y, wr[5], Ar); Az = fmaf(e23.y, wz[5], Az); Ani = fmaf(e23.y, wn[5], Ani);
        Ar = fmaf(e23.z, wr[6], Ar); Az = fmaf(e23.z, wz[6], Az); Ani = fmaf(e23.z, wn[6], Ani);
        Ar = fmaf(e23.w, wr[7], Ar); Az = fmaf(e23.w, wz[7], Az); Ani = fmaf(e23.w, wn[7], Ani);

        Ar = fmaf(h0.x, ur[0], Ar);  Az = fmaf(h0.x, uz[0], Az);  Anh = fmaf(h0.x, un[0], Anh);
        Ar = fmaf(h0.y, ur[1], Ar);  Az = fmaf(h0.y, uz[1], Az);  Anh = fmaf(h0.y, un[1], Anh);
        Ar = fmaf(h0.z, ur[2], Ar);  Az = fmaf(h0.z, uz[2], Az);  Anh = fmaf(h0.z, un[2], Anh);
        Ar = fmaf(h0.w, ur[3], Ar);  Az = fmaf(h0.w, uz[3], Az);  Anh = fmaf(h0.w, un[3], Anh);
        Ar = fmaf(h1.x, ur[4], Ar);  Az = fmaf(h1.x, uz[4], Az);  Anh = fmaf(h1.x, un[4], Anh);
        Ar = fmaf(h1.y, ur[5], Ar);  Az = fmaf(h1.y, uz[5], Az);  Anh = fmaf(h1.y, un[5], Anh);
        Ar = fmaf(h1.z, ur[6], Ar);  Az = fmaf(h1.z, uz[6], Az);  Anh = fmaf(h1.z, un[6], Anh);
        Ar = fmaf(h1.w, ur[7], Ar);  Az = fmaf(h1.w, uz[7], Az);  Anh = fmaf(h1.w, un[7], Anh);
        Ar = fmaf(h2.x, ur[8], Ar);  Az = fmaf(h2.x, uz[8], Az);  Anh = fmaf(h2.x, un[8], Anh);
        Ar = fmaf(h2.y, ur[9], Ar);  Az = fmaf(h2.y, uz[9], Az);  Anh = fmaf(h2.y, un[9], Anh);
        Ar = fmaf(h2.z, ur[10], Ar); Az = fmaf(h2.z, uz[10], Az); Anh = fmaf(h2.z, un[10], Anh);
        Ar = fmaf(h2.w, ur[11], Ar); Az = fmaf(h2.w, uz[11], Az); Anh = fmaf(h2.w, un[11], Anh);
        Ar = fmaf(h3.x, ur[12], Ar); Az = fmaf(h3.x, uz[12], Az); Anh = fmaf(h3.x, un[12], Anh);
        Ar = fmaf(h3.y, ur[13], Ar); Az = fmaf(h3.y, uz[13], Az); Anh = fmaf(h3.y, un[13], Anh);
        Ar = fmaf(h3.z, ur[14], Ar); Az = fmaf(h3.z, uz[14], Az); Anh = fmaf(h3.z, un[14], Anh);
        Ar = fmaf(h3.w, ur[15], Ar); Az = fmaf(h3.w, uz[15], Az); Anh = fmaf(h3.w, un[15], Anh);

        // combine p-halves exactly as R0 (ds_bpermute l^32), but issue all
        // four back-to-back so they share one DS latency.
        float tr  = bperm(aX, Ar);
        float tz  = bperm(aX, Az);
        float tni = bperm(aX, Ani);
        float tnh = bperm(aX, Anh);
        Ar  += tr;
        Az  += tz;
        Ani += tni;
        Anh += tnh;

        float r = fast_sigmoid(Ar);
        float z = fast_sigmoid(Az);
        float cand = fast_tanh(fmaf(r, Anh, Ani));
        h = (1.f - z) * cand + z * h;

        if (l < 32) lh[wv][l] = h;          // publish h for next step ASAP
        *op = __float2bfloat16(h);          // both halves write same value: ok

        // me for next step from prefetched x (independent of h-chain)
        float e0 = ebias;
        e0 = fmaf(nx0.x, ew[0], e0); e0 = fmaf(nx0.y, ew[1], e0);
        e0 = fmaf(nx0.z, ew[2], e0); e0 = fmaf(nx0.w, ew[3], e0);
        e0 = fmaf(nx1.x, ew[4], e0); e0 = fmaf(nx1.y, ew[5], e0);
        e0 = fmaf(nx1.z, ew[6], e0); e0 = fmaf(nx1.w, ew[7], e0);
        me = fmaxf(e0, 0.f);
        if (l < 16) lme[wv][l] = me;

        xp = np; op += ostep;
    }
    hT[b * 64 + dir * 32 + j] = h;
}

// ---------------------------------------------------------------------------
// s0 = tanh([hTf,hTb] @ act_w^T + act_b); sWs0 = s0 @ Ws^T; dec_in0 = x[:,511,0].
// Also zeroes the 24*512 softmax denominators (block 0). grid 128 x 256.
// ---------------------------------------------------------------------------
__global__ __launch_bounds__(256) void s0_kernel(
    const float* __restrict__ hT, const float* __restrict__ act_w, const float* __restrict__ act_b,
    const float* __restrict__ attn_w, const float* __restrict__ x,
    float* __restrict__ s, float* __restrict__ sWs, float* __restrict__ dec_in,
    float* __restrict__ denom)
{
    if (blockIdx.x == 0){
        for (int i = threadIdx.x; i < 24 * 512; i += 256) denom[i] = 0.f;
    }
    int j = threadIdx.x & 31, g = threadIdx.x >> 5;
    int b = blockIdx.x * 8 + g;
    float acc = act_b[j];
    const float4* aw = (const float4*)(act_w + j * 64);
    const float4* hp = (const float4*)(hT + b * 64);
#pragma unroll
    for (int c = 0; c < 16; c++){
        float4 wv = aw[c]; float4 hv = hp[c];
        acc = fmaf(hv.x, wv.x, acc); acc = fmaf(hv.y, wv.y, acc);
        acc = fmaf(hv.z, wv.z, acc); acc = fmaf(hv.w, wv.w, acc);
    }
    float s0v = fast_tanh(acc);
    s[b * 32 + j] = s0v;
    __shared__ float ssh[8][33];
    ssh[g][j] = s0v;
    __syncthreads();
    float a = 0.f;
    const float4* wsp = (const float4*)(attn_w + j * 96);   // Ws = attn_w[:, :32]
#pragma unroll
    for (int c = 0; c < 8; c++){
        float4 wv = wsp[c];
        a = fmaf(ssh[g][4 * c + 0], wv.x, a);
        a = fmaf(ssh[g][4 * c + 1], wv.y, a);
        a = fmaf(ssh[g][4 * c + 2], wv.z, a);
        a = fmaf(ssh[g][4 * c + 3], wv.w, a);
    }
    sWs[b * 32 + j] = a;
    if (j == 0) dec_in[b] = x[(size_t)b * 4096 + 511 * 8];
}

// ---------------------------------------------------------------------------
// enc_proj[t,b,j] = sum_d enc_outT[b,t,d] * We[j,d];  We = attn_w[:, 32:96]
// Reads enc_outT rows ([b][t][64] contiguous), writes proj in [t][b][32].
// grid 2048 x 256.
// ---------------------------------------------------------------------------
__global__ __launch_bounds__(256) void proj_kernel(
    const __hip_bfloat16* __restrict__ enc_outT, const float* __restrict__ attn_w,
    __hip_bfloat16* __restrict__ proj)
{
    int j = threadIdx.x & 31, g = threadIdx.x >> 5;
    float w[64];
    const float4* aw = (const float4*)(attn_w + j * 96 + 32);
#pragma unroll
    for (int c = 0; c < 16; c++){
        float4 q = aw[c];
        w[4 * c] = q.x; w[4 * c + 1] = q.y; w[4 * c + 2] = q.z; w[4 * c + 3] = q.w;
    }
    size_t base = (size_t)blockIdx.x * 256 + g * 32;
    for (int r = 0; r < 32; ++r){
        size_t pl = base + r;                      // pl = b*512 + t
        const uint4* ev = (const uint4*)(enc_outT + pl * 64);
        float acc = 0.f;
#pragma unroll
        for (int c = 0; c < 8; c++){
            uint4 pk = ev[c];
            acc = fmaf(bflo(pk.x), w[8 * c + 0], acc);
            acc = fmaf(bfhi(pk.x), w[8 * c + 1], acc);
            acc = fmaf(bflo(pk.y), w[8 * c + 2], acc);
            acc = fmaf(bfhi(pk.y), w[8 * c + 3], acc);
            acc = fmaf(bflo(pk.z), w[8 * c + 4], acc);
            acc = fmaf(bfhi(pk.z), w[8 * c + 5], acc);
            acc = fmaf(bflo(pk.w), w[8 * c + 6], acc);
            acc = fmaf(bfhi(pk.w), w[8 * c + 7], acc);
        }
        int t = (int)(pl & 511);
        int bb = (int)(pl >> 9);
        proj[((size_t)t * 1024 + bb) * 32 + j] = __float2bfloat16(acc);
    }
}

// ---------------------------------------------------------------------------
// Attention scores: E[t,b] = exp(sum_j v[j]*tanh(sWs[b,j]+proj[t,b,j]));
// denom[t] += block partial. grid 2048 (= 512 t * 4 b-chunks).
// ---------------------------------------------------------------------------
__global__ __launch_bounds__(256) void attn_kernel(
    const __hip_bfloat16* __restrict__ proj, const float* __restrict__ sWs,
    const float* __restrict__ attn_v, float* __restrict__ Ebuf, float* __restrict__ denom)
{
    int t = blockIdx.x >> 2;
    int b = (blockIdx.x & 3) * 256 + threadIdx.x;
    float v[32];
    {
        const float4* vv = (const float4*)attn_v;
#pragma unroll
        for (int c = 0; c < 8; c++){
            float4 q = vv[c];
            v[4 * c] = q.x; v[4 * c + 1] = q.y; v[4 * c + 2] = q.z; v[4 * c + 3] = q.w;
        }
    }
    const uint4* pp = (const uint4*)(proj + ((size_t)t * 1024 + b) * 32);
    const float4* sp = (const float4*)(sWs + b * 32);
    float acc = 0.f;
#pragma unroll
    for (int c = 0; c < 4; c++){
        uint4 pk = pp[c];
        float4 s0 = sp[2 * c], s1 = sp[2 * c + 1];
        acc = fmaf(v[8 * c + 0], fast_tanh(s0.x + bflo(pk.x)), acc);
        acc = fmaf(v[8 * c + 1], fast_tanh(s0.y + bfhi(pk.x)), acc);
        acc = fmaf(v[8 * c + 2], fast_tanh(s0.z + bflo(pk.y)), acc);
        acc = fmaf(v[8 * c + 3], fast_tanh(s0.w + bfhi(pk.y)), acc);
        acc = fmaf(v[8 * c + 4], fast_tanh(s1.x + bflo(pk.z)), acc);
        acc = fmaf(v[8 * c + 5], fast_tanh(s1.y + bfhi(pk.z)), acc);
        acc = fmaf(v[8 * c + 6], fast_tanh(s1.z + bflo(pk.w)), acc);
        acc = fmaf(v[8 * c + 7], fast_tanh(s1.w + bfhi(pk.w)), acc);
    }
    float Ev = __builtin_amdgcn_exp2f(LOG2E * acc);
    Ebuf[(size_t)t * 1024 + b] = Ev;
    float r = Ev;
#pragma unroll
    for (int o = 32; o >= 1; o >>= 1) r += __shfl_xor(r, o, 64);
    __shared__ float wsum[4];
    if ((threadIdx.x & 63) == 0) wsum[threadIdx.x >> 6] = r;
    __syncthreads();
    if (threadIdx.x == 0) atomicAdd(denom + t, wsum[0] + wsum[1] + wsum[2] + wsum[3]);
}

// ---------------------------------------------------------------------------
// Decoder step v2: block b. E-column + denom -> LDS weights (parallel scalar
// loads); ctx from enc_outT[b] = contiguous 64KB via coalesced uint4 loads;
// shuffle-reduce; GRU cell + fc + next sWs. grid 1024 x 256.
// ---------------------------------------------------------------------------
__global__ __launch_bounds__(256) void dec_kernel(
    const __hip_bfloat16* __restrict__ enc_outT, const float* __restrict__ Ebuf,
    const float* __restrict__ denom, float* __restrict__ s, float* __restrict__ sWs,
    float* __restrict__ dec_in,
    const float* __restrict__ demb_w, const float* __restrict__ demb_b,
    const float* __restrict__ dwih, const float* __restrict__ dwhh,
    const float* __restrict__ dbih, const float* __restrict__ dbhh,
    const float* __restrict__ attn_w, const float* __restrict__ fc_w,
    const float* __restrict__ fc_b, float* __restrict__ out, int step)
{
    __shared__ float w_sh[512];
    __shared__ float ctxp[4][64];
    __shared__ float rnn_sh[80];    // [embd(16), ctx(64)]
    __shared__ float scur[32];
    __shared__ float gsum[64];
    __shared__ float gin[32], ghn[32];
    __shared__ float snew[32];
    int tid = threadIdx.x;
    int b = blockIdx.x;
    int wv = tid >> 6, l = tid & 63;

    // softmax weights for this b: w[t] = E[t][b] / denom[t]
    float d0 = denom[tid], d1 = denom[tid + 256];
    float e0 = Ebuf[(size_t)tid * 1024 + b];
    float e1 = Ebuf[(size_t)(tid + 256) * 1024 + b];
    w_sh[tid] = e0 * __builtin_amdgcn_rcpf(d0);
    w_sh[tid + 256] = e1 * __builtin_amdgcn_rcpf(d1);
    if (tid < 16) rnn_sh[tid] = fmaxf(fmaf(dec_in[b], demb_w[tid], demb_b[tid]), 0.f);
    if (tid >= 32 && tid < 64) scur[tid - 32] = s[b * 32 + tid - 32];
    __syncthreads();

    // ctx: contiguous 64KB sweep; thread handles d-octet (tid&7), t = i*32+(tid>>3)
    float acc0 = 0.f, acc1 = 0.f, acc2 = 0.f, acc3 = 0.f;
    float acc4 = 0.f, acc5 = 0.f, acc6 = 0.f, acc7 = 0.f;
    const uint4* ep = (const uint4*)(enc_outT + (size_t)b * 32768);
#pragma unroll
    for (int i = 0; i < 16; i++){
        int idx = i * 256 + tid;
        uint4 pk = ep[idx];
        float wgt = w_sh[idx >> 3];
        acc0 = fmaf(wgt, bflo(pk.x), acc0);
        acc1 = fmaf(wgt, bfhi(pk.x), acc1);
        acc2 = fmaf(wgt, bflo(pk.y), acc2);
        acc3 = fmaf(wgt, bfhi(pk.y), acc3);
        acc4 = fmaf(wgt, bflo(pk.z), acc4);
        acc5 = fmaf(wgt, bfhi(pk.z), acc5);
        acc6 = fmaf(wgt, bflo(pk.w), acc6);
        acc7 = fmaf(wgt, bfhi(pk.w), acc7);
    }
#pragma unroll
    for (int o = 8; o <= 32; o <<= 1){
        acc0 += __shfl_xor(acc0, o, 64); acc1 += __shfl_xor(acc1, o, 64);
        acc2 += __shfl_xor(acc2, o, 64); acc3 += __shfl_xor(acc3, o, 64);
        acc4 += __shfl_xor(acc4, o, 64); acc5 += __shfl_xor(acc5, o, 64);
        acc6 += __shfl_xor(acc6, o, 64); acc7 += __shfl_xor(acc7, o, 64);
    }
    if (l < 8){
        float* cp = &ctxp[wv][l * 8];
        cp[0] = acc0; cp[1] = acc1; cp[2] = acc2; cp[3] = acc3;
        cp[4] = acc4; cp[5] = acc5; cp[6] = acc6; cp[7] = acc7;
    }
    __syncthreads();
    if (tid < 64) rnn_sh[16 + tid] = ctxp[0][tid] + ctxp[1][tid] + ctxp[2][tid] + ctxp[3][tid];
    __syncthreads();

    if (tid < 96){
        int row = tid;
        float gi = dbih[row];
        const float4* wr = (const float4*)(dwih + row * 80);
#pragma unroll
        for (int c = 0; c < 20; c++){
            float4 wv4 = wr[c];
            gi = fmaf(rnn_sh[4 * c + 0], wv4.x, gi);
            gi = fmaf(rnn_sh[4 * c + 1], wv4.y, gi);
            gi = fmaf(rnn_sh[4 * c + 2], wv4.z, gi);
            gi = fmaf(rnn_sh[4 * c + 3], wv4.w, gi);
        }
        float gh = dbhh[row];
        const float4* urow = (const float4*)(dwhh + row * 32);
#pragma unroll
        for (int c = 0; c < 8; c++){
            float4 wv4 = urow[c];
            gh = fmaf(scur[4 * c + 0], wv4.x, gh);
            gh = fmaf(scur[4 * c + 1], wv4.y, gh);
            gh = fmaf(scur[4 * c + 2], wv4.z, gh);
            gh = fmaf(scur[4 * c + 3], wv4.w, gh);
        }
        if (row < 64) gsum[row] = gi + gh;
        else { gin[row - 64] = gi; ghn[row - 64] = gh; }
    }
    __syncthreads();

    if (tid < 32){
        float r = fast_sigmoid(gsum[tid]);
        float z = fast_sigmoid(gsum[32 + tid]);
        float cand = fast_tanh(fmaf(r, ghn[tid], gin[tid]));
        float sn = (1.f - z) * cand + z * scur[tid];
        snew[tid] = sn;
        s[b * 32 + tid] = sn;
    }
    __syncthreads();

    if (tid < 32){   // next-step sWs
        float a = 0.f;
        const float4* aw = (const float4*)(attn_w + tid * 96);
#pragma unroll
        for (int c = 0; c < 8; c++){
            float4 wv4 = aw[c];
            a = fmaf(snew[4 * c + 0], wv4.x, a);
            a = fmaf(snew[4 * c + 1], wv4.y, a);
            a = fmaf(snew[4 * c + 2], wv4.z, a);
            a = fmaf(snew[4 * c + 3], wv4.w, a);
        }
        sWs[b * 32 + tid] = a;
    } else if (tid >= 64 && tid < 128){   // fc: pred = cat(112) . fc_w + fc_b
        int ll = tid - 64;
        float cv0 = (ll < 32) ? snew[ll] : rnn_sh[ll - 16];
        float p = cv0 * fc_w[ll];
        if (ll < 48){
            int i = 64 + ll;
            float cv1 = (i < 96) ? rnn_sh[i - 16] : rnn_sh[i - 96];
            p = fmaf(cv1, fc_w[i], p);
        }
#pragma unroll
        for (int o = 32; o >= 1; o >>= 1) p += __shfl_xor(p, o, 64);
        if (ll == 0){
            float pred = p + fc_b[0];
            out[b * 24 + step] = pred;
            dec_in[b] = pred;
        }
    }
}

// ---------------------------------------------------------------------------
extern "C" void kernel_launch(void* const* d_in, const int* in_sizes, int n_in,
                              void* d_out, int out_size, void* d_ws, size_t ws_size,
                              hipStream_t stream)
{
    const float* x      = (const float*)d_in[0];
    const float* emb_w  = (const float*)d_in[2];
    const float* emb_b  = (const float*)d_in[3];
    const float* wih_f  = (const float*)d_in[4];
    const float* whh_f  = (const float*)d_in[5];
    const float* bih_f  = (const float*)d_in[6];
    const float* bhh_f  = (const float*)d_in[7];
    const float* wih_b  = (const float*)d_in[8];
    const float* whh_b  = (const float*)d_in[9];
    const float* bih_b  = (const float*)d_in[10];
    const float* bhh_b  = (const float*)d_in[11];
    const float* act_w  = (const float*)d_in[12];
    const float* act_b  = (const float*)d_in[13];
    const float* attn_w = (const float*)d_in[14];
    const float* attn_v = (const float*)d_in[15];
    const float* demb_w = (const float*)d_in[16];
    const float* demb_b = (const float*)d_in[17];
    const float* dwih   = (const float*)d_in[18];
    const float* dwhh   = (const float*)d_in[19];
    const float* dbih   = (const float*)d_in[20];
    const float* dbhh   = (const float*)d_in[21];
    const float* fc_w   = (const float*)d_in[22];
    const float* fc_b   = (const float*)d_in[23];
    (void)in_sizes; (void)n_in; (void)out_size; (void)ws_size;

    char* w = (char*)d_ws;
    __hip_bfloat16* enc_outT = (__hip_bfloat16*)w;                // [b][t][64] bf16, 67108864 B
    __hip_bfloat16* proj     = (__hip_bfloat16*)(w + 67108864);   // [t][b][32] bf16, 33554432 B
    float* hT     = (float*)(w + 100663296);                      // 1024*64*4
    float* s      = (float*)(w + 100925440);                      // 1024*32*4
    float* sWs    = (float*)(w + 101056512);                      // 1024*32*4
    float* Ebuf   = (float*)(w + 101187584);                      // [t][b] f32, 2097152 B
    float* denom  = (float*)(w + 103284736);                      // 24*512*4
    float* dec_in = (float*)(w + 103333888);                      // 1024*4
    float* out = (float*)d_out;

    enc_kernel<<<512, 256, 0, stream>>>(x, emb_w, emb_b, wih_f, whh_f, bih_f, bhh_f,
                                        wih_b, whh_b, bih_b, bhh_b, enc_outT, hT);
    s0_kernel<<<128, 256, 0, stream>>>(hT, act_w, act_b, attn_w, x, s, sWs, dec_in, denom);
    proj_kernel<<<2048, 256, 0, stream>>>(enc_outT, attn_w, proj);
    for (int st = 0; st < 24; ++st){
        attn_kernel<<<2048, 256, 0, stream>>>(proj, sWs, attn_v, Ebuf, denom + st * 512);
        dec_kernel<<<1024, 256, 0, stream>>>(enc_outT, Ebuf, denom + st * 512, s, sWs, dec_in,
                                             demb_w, demb_b, dwih, dwhh, dbih, dbhh,
                                             attn_w, fc_w, fc_b, out, st);
    }
}